// Round 9
// baseline (77.844 us; speedup 1.0000x reference)
//
#include <hip/hip_runtime.h>
#include <hip/hip_bf16.h>

#define NSEN 4000
#define NP   4096
#define DIN  128
#define DOUT 128
#define EDIM 16
#define BATCH 8

typedef __attribute__((ext_vector_type(8))) short bf16x8;
typedef __attribute__((ext_vector_type(4))) float f32x4;

__device__ __forceinline__ unsigned short f2bf(float f) {
  unsigned int u = __float_as_uint(f);
  unsigned int r = (u + 0x7FFFu + ((u >> 16) & 1u)) >> 16;
  return (unsigned short)r;
}
__device__ __forceinline__ float bf2f(unsigned short s) {
  unsigned int u = ((unsigned int)s) << 16;
  return __uint_as_float(u);
}

__device__ __forceinline__ void gl_lds16(const void* g, void* l) {
  __builtin_amdgcn_global_load_lds((const __attribute__((address_space(1))) void*)g,
                                   (__attribute__((address_space(3))) void*)l, 16, 0, 0);
}

// ---------------- Kernel 1 (merged prep) -----------------------------------------
// blocks 0..249:  P = exp(relu(E1 @ E2^T)) unnormalized -> adjp bf16 ; rinv = 1/rowsum
// blocks 250..761: yt[b*128+o][m] = bf16( (x @ W)[b,m,o] ), cols m>=NSEN -> 0
//                 (algebraic reorder: (adj@x)@W == adj@(x@W); W-frags read from f32 W)
__global__ __launch_bounds__(512) void k_prep(const float* __restrict__ E1,
                                              const float* __restrict__ E2,
                                              const float* __restrict__ W,
                                              const float* __restrict__ x,
                                              unsigned short* __restrict__ adjp,
                                              float* __restrict__ rinv,
                                              unsigned short* __restrict__ yt) {
  __shared__ float rsum[8][16];
  const int bx = blockIdx.x;
  const int tid = threadIdx.x;
  const int lane = tid & 63, wv = tid >> 6;
  const int lr = lane & 15, lq = lane >> 4;

  if (bx >= 250) {
    // ---- y^T tile GEMM: yi -> (batch b, 64-m tile mt) ----
    const int yi = bx - 250;        // 0..511
    const int b  = yi >> 6;         // 0..7
    const int mt = yi & 63;         // 0..63  (m0 up to 4032: covers full K pad)
    const int m0 = mt * 64;
    const int mh = wv >> 2;         // 0..1 : 32-m half
    const int os = wv & 3;          // 0..3 : 32-o strip
    // A-frags = W^T[o][f] from f32 W (64 KB, L2-hot)
    bf16x8 af[2][4];
#pragma unroll
    for (int ot = 0; ot < 2; ot++) {
      const int ob = os * 32 + ot * 16 + lr;
#pragma unroll
      for (int ks = 0; ks < 4; ks++)
#pragma unroll
        for (int j = 0; j < 8; j++)
          af[ot][ks][j] = (short)f2bf(W[(size_t)(ks * 32 + lq * 8 + j) * DOUT + ob]);
    }
#pragma unroll
    for (int mtile = 0; mtile < 2; mtile++) {
      const int mb = m0 + mh * 32 + mtile * 16;
      const int m = mb + lr;
      bf16x8 bx8[4];
      if (m < NSEN) {
        const float* xp = &x[((size_t)b * NSEN + m) * DIN + lq * 8];
#pragma unroll
        for (int ks = 0; ks < 4; ks++) {
          float4 v0 = *(const float4*)(xp + ks * 32);
          float4 v1 = *(const float4*)(xp + ks * 32 + 4);
          bx8[ks][0] = (short)f2bf(v0.x); bx8[ks][1] = (short)f2bf(v0.y);
          bx8[ks][2] = (short)f2bf(v0.z); bx8[ks][3] = (short)f2bf(v0.w);
          bx8[ks][4] = (short)f2bf(v1.x); bx8[ks][5] = (short)f2bf(v1.y);
          bx8[ks][6] = (short)f2bf(v1.z); bx8[ks][7] = (short)f2bf(v1.w);
        }
      } else {
#pragma unroll
        for (int ks = 0; ks < 4; ks++)
#pragma unroll
          for (int j = 0; j < 8; j++) bx8[ks][j] = 0;
      }
#pragma unroll
      for (int ot = 0; ot < 2; ot++) {
        f32x4 c = (f32x4){0.f, 0.f, 0.f, 0.f};
#pragma unroll
        for (int ks = 0; ks < 4; ks++)
          c = __builtin_amdgcn_mfma_f32_16x16x32_bf16(af[ot][ks], bx8[ks], c, 0, 0, 0);
        // C: col = lr (m-local), row = lq*4+i (o-local)
#pragma unroll
        for (int i = 0; i < 4; i++)
          yt[(size_t)(b * 128 + os * 32 + ot * 16 + lq * 4 + i) * NP + mb + lr] = f2bf(c[i]);
      }
    }
    return;
  }

  // ---- adjacency rows n0..n0+15 (MFMA hi/lo split) ----
  const int n0 = bx * 16;

  float a[8];
  {
    const float* e1p = &E1[(size_t)(n0 + lr) * EDIM + (lq & 1) * 8];
    *(float4*)&a[0] = *(const float4*)e1p;
    *(float4*)&a[4] = *(const float4*)(e1p + 4);
  }
  bf16x8 af1, af2;
#pragma unroll
  for (int j = 0; j < 8; j++) {
    unsigned short hs = f2bf(a[j]);
    af1[j] = (short)hs;
    float lo = a[j] - bf2f(hs);
    af2[j] = (lq < 2) ? (short)f2bf(lo) : (short)0;
  }

  float rs[4] = {0.f, 0.f, 0.f, 0.f};
  for (int t = wv; t < NSEN / 16; t += 8) {
    const int m = t * 16 + lr;
    float bv[8];
    const float* e2p = &E2[(size_t)m * EDIM + (lq & 1) * 8];
    *(float4*)&bv[0] = *(const float4*)e2p;
    *(float4*)&bv[4] = *(const float4*)(e2p + 4);
    bf16x8 bfrag;
#pragma unroll
    for (int j = 0; j < 8; j++) {
      unsigned short hs = f2bf(bv[j]);
      if (lq < 2) bfrag[j] = (short)hs;
      else        bfrag[j] = (short)f2bf(bv[j] - bf2f(hs));
    }
    f32x4 c = (f32x4){0.f, 0.f, 0.f, 0.f};
    c = __builtin_amdgcn_mfma_f32_16x16x32_bf16(af1, bfrag, c, 0, 0, 0);
    c = __builtin_amdgcn_mfma_f32_16x16x32_bf16(af2, bfrag, c, 0, 0, 0);
#pragma unroll
    for (int i = 0; i < 4; i++) {
      float p = __expf(fmaxf(c[i], 0.f));
      rs[i] += p;
      adjp[(size_t)(n0 + lq * 4 + i) * NP + t * 16 + lr] = f2bf(p);
    }
  }
  for (int i = tid; i < 16 * (NP - NSEN); i += 512) {
    int r = i / (NP - NSEN), c = i % (NP - NSEN);
    adjp[(size_t)(n0 + r) * NP + NSEN + c] = 0;
  }
#pragma unroll
  for (int i = 0; i < 4; i++) {
    rs[i] += __shfl_xor(rs[i], 1, 64);
    rs[i] += __shfl_xor(rs[i], 2, 64);
    rs[i] += __shfl_xor(rs[i], 4, 64);
    rs[i] += __shfl_xor(rs[i], 8, 64);
  }
  if (lr == 0) {
#pragma unroll
    for (int i = 0; i < 4; i++) rsum[wv][lq * 4 + i] = rs[i];
  }
  __syncthreads();
  if (tid < 16) {
    float s = 0.f;
#pragma unroll
    for (int w = 0; w < 8; w++) s += rsum[w][tid];
    rinv[n0 + tid] = 1.0f / s;
  }
}

// ---------------- Kernel 2: split-K partial GEMM  part[kh] = P[:,kh] @ yt^T ------
// (unchanged from R8 — proven 785 TF / 43.8 us, FETCH 34 MB, 0 bank conflicts)
__global__ __launch_bounds__(256, 2) void k_gemm1(const unsigned short* __restrict__ A,
                                                  const unsigned short* __restrict__ Bt,
                                                  unsigned short* __restrict__ part) {
  __shared__ __align__(16) unsigned short smem[32768];  // 64 KB: A 2x8192 | B 2x8192
  const int tid = threadIdx.x;
  const int lane = tid & 63, wv = tid >> 6;
  const int wr = wv >> 1, wc = wv & 1;     // 2 x 2 wave grid, wave tile 64x64
  const int lr = lane & 15, lq = lane >> 4;
  const int gx = blockIdx.x;               // 0..63 = 2*mtile + kh
  const int m0 = (gx >> 1) * 128;
  const int kb0 = (gx & 1) * 2048;
  const int b  = blockIdx.y;
  const int c0 = b * 128;
  unsigned short* tA0 = smem;            // 2 * 8192 shorts
  unsigned short* tB0 = smem + 16384;    // 2 * 8192 shorts

  f32x4 acc[4][4];
#pragma unroll
  for (int p = 0; p < 4; p++)
#pragma unroll
    for (int q = 0; q < 4; q++) acc[p][q] = (f32x4){0.f, 0.f, 0.f, 0.f};

#define STAGE(bufi, kb)                                                              \
  {                                                                                  \
    _Pragma("unroll")                                                                \
    for (int s = 0; s < 4; s++) {                                                    \
      int idx = s * 256 + tid;                                                       \
      int row = idx >> 3;                                                            \
      int kc = ((idx & 7) ^ (row & 7)) << 3;                                         \
      gl_lds16(&A[(size_t)(m0 + row) * NP + (kb) + kc], &tA0[(bufi)*8192 + idx*8]);  \
      gl_lds16(&Bt[(size_t)(c0 + row) * NP + (kb) + kc], &tB0[(bufi)*8192 + idx*8]); \
    }                                                                                \
  }

  STAGE(0, kb0);

  for (int it = 0; it < 32; ++it) {
    const int cur = it & 1;
    if (it < 31) {
      STAGE(cur ^ 1, kb0 + (it + 1) * 64);
      asm volatile("s_waitcnt vmcnt(8)" ::: "memory");
    } else {
      asm volatile("s_waitcnt vmcnt(0)" ::: "memory");
    }
    __builtin_amdgcn_s_barrier();

    bf16x8 af0[4], bf0[4], af1[4], bf1[4];
    {
      const int koff0 = (lq * 8) ^ ((lr & 7) << 3);
#pragma unroll
      for (int p = 0; p < 4; p++)
        af0[p] = *(const bf16x8*)&tA0[cur * 8192 + (wr * 64 + p * 16 + lr) * 64 + koff0];
#pragma unroll
      for (int q = 0; q < 4; q++)
        bf0[q] = *(const bf16x8*)&tB0[cur * 8192 + (wc * 64 + q * 16 + lr) * 64 + koff0];
    }
    __builtin_amdgcn_sched_barrier(0);
    {
      const int koff1 = (32 + lq * 8) ^ ((lr & 7) << 3);
#pragma unroll
      for (int p = 0; p < 4; p++)
        af1[p] = *(const bf16x8*)&tA0[cur * 8192 + (wr * 64 + p * 16 + lr) * 64 + koff1];
#pragma unroll
      for (int q = 0; q < 4; q++)
        bf1[q] = *(const bf16x8*)&tB0[cur * 8192 + (wc * 64 + q * 16 + lr) * 64 + koff1];
    }
    asm volatile("s_waitcnt lgkmcnt(8)" ::: "memory");
    __builtin_amdgcn_sched_barrier(0);
    __builtin_amdgcn_s_setprio(1);
#pragma unroll
    for (int p = 0; p < 4; p++)
#pragma unroll
      for (int q = 0; q < 4; q++)
        acc[p][q] = __builtin_amdgcn_mfma_f32_16x16x32_bf16(af0[p], bf0[q], acc[p][q], 0, 0, 0);
    asm volatile("s_waitcnt lgkmcnt(0)" ::: "memory");
    __builtin_amdgcn_sched_barrier(0);
#pragma unroll
    for (int p = 0; p < 4; p++)
#pragma unroll
      for (int q = 0; q < 4; q++)
        acc[p][q] = __builtin_amdgcn_mfma_f32_16x16x32_bf16(af1[p], bf1[q], acc[p][q], 0, 0, 0);
    __builtin_amdgcn_s_setprio(0);
    __builtin_amdgcn_s_barrier();
  }
#undef STAGE

  const int kh = gx & 1;
  unsigned short* pdst = part + ((size_t)(kh * BATCH + b) * NP + m0) * DIN;
#pragma unroll
  for (int p = 0; p < 4; p++)
#pragma unroll
    for (int q = 0; q < 4; q++) {
      const int col = wc * 64 + q * 16 + lr;
#pragma unroll
      for (int i = 0; i < 4; i++) {
        const int row = wr * 64 + p * 16 + lq * 4 + i;
        pdst[row * DIN + col] = f2bf(acc[p][q][i]);
      }
    }
}

// ---------------- Kernel 3: out = relu((p0+p1)*rinv + bias)  (pure elementwise) --
__global__ __launch_bounds__(256) void k_fin(const unsigned short* __restrict__ part,
                                             const float* __restrict__ rinv,
                                             const float* __restrict__ bias,
                                             float* __restrict__ out) {
  const int tid = threadIdx.x;
  const int nl = tid >> 4;        // 0..15 row within block
  const int ch = tid & 15;        // 0..15 chunk of 8 outputs
  const int n  = blockIdx.x * 16 + nl;   // < 4000
  const int b  = blockIdx.y;
  const size_t base = ((size_t)b * NP + n) * DIN + ch * 8;
  const size_t khoff = (size_t)BATCH * NP * DIN;

  bf16x8 p0 = *(const bf16x8*)&part[base];
  bf16x8 p1 = *(const bf16x8*)&part[khoff + base];
  const float rv = rinv[n];
  float4 bb0 = *(const float4*)&bias[ch * 8];
  float4 bb1 = *(const float4*)&bias[ch * 8 + 4];
  float r[8];
#pragma unroll
  for (int j = 0; j < 8; j++) {
    float bbj = (j < 4) ? ((const float*)&bb0)[j] : ((const float*)&bb1)[j - 4];
    r[j] = fmaxf((bf2f((unsigned short)p0[j]) + bf2f((unsigned short)p1[j])) * rv + bbj, 0.f);
  }
  float* op = &out[((size_t)b * NSEN + n) * DOUT + ch * 8];
  *(float4*)op       = make_float4(r[0], r[1], r[2], r[3]);
  *(float4*)(op + 4) = make_float4(r[4], r[5], r[6], r[7]);
}

// ---------------- launch ---------------------------------------------------------
extern "C" void kernel_launch(void* const* d_in, const int* in_sizes, int n_in,
                              void* d_out, int out_size, void* d_ws, size_t ws_size,
                              hipStream_t stream) {
  const float* x    = (const float*)d_in[0];
  const float* E1   = (const float*)d_in[1];
  const float* E2   = (const float*)d_in[2];
  const float* W    = (const float*)d_in[3];
  const float* bias = (const float*)d_in[4];
  float* out = (float*)d_out;

  char* ws = (char*)d_ws;
  // layout: adjp 33554432 | yt 8388608 | rinv 16384 | part 16777216  (~57 MiB)
  unsigned short* adjp = (unsigned short*)(ws);
  unsigned short* yt   = (unsigned short*)(ws + 33554432);
  float*          rinv = (float*)(ws + 33554432 + 8388608);
  unsigned short* part = (unsigned short*)(ws + 33554432 + 8388608 + 16384);

  k_prep<<<dim3(762), dim3(512), 0, stream>>>(E1, E2, W, x, adjp, rinv, yt);
  k_gemm1<<<dim3(64, BATCH), dim3(256), 0, stream>>>(adjp, yt, part);
  k_fin<<<dim3(250, BATCH), dim3(256), 0, stream>>>(part, rinv, bias, out);
}

// Round 10
// 77.464 us; speedup vs baseline: 1.0049x; 1.0049x over previous
//
#include <hip/hip_runtime.h>
#include <hip/hip_bf16.h>

#define NSEN 4000
#define NP   4096
#define DIN  128
#define DOUT 128
#define EDIM 16
#define BATCH 8

typedef __attribute__((ext_vector_type(8))) short bf16x8;
typedef __attribute__((ext_vector_type(4))) float f32x4;

__device__ __forceinline__ unsigned short f2bf(float f) {
  unsigned int u = __float_as_uint(f);
  unsigned int r = (u + 0x7FFFu + ((u >> 16) & 1u)) >> 16;
  return (unsigned short)r;
}
__device__ __forceinline__ float bf2f(unsigned short s) {
  unsigned int u = ((unsigned int)s) << 16;
  return __uint_as_float(u);
}

__device__ __forceinline__ void gl_lds16(const void* g, void* l) {
  __builtin_amdgcn_global_load_lds((const __attribute__((address_space(1))) void*)g,
                                   (__attribute__((address_space(3))) void*)l, 16, 0, 0);
}

// ---------------- Kernel 1 (merged prep) -----------------------------------------
// blocks 0..249:   P = exp(relu(E1 @ E2^T)) unnormalized -> adjp bf16 ; rinv = 1/rowsum
// blocks 250..377: yt[b*128+o][m] = bf16( (x @ W)[b,m,o] ), cols m>=NSEN -> 0.
//   W staged once per block into LDS (coalesced), A-frags via ds_read_b128.
__global__ __launch_bounds__(512) void k_prep(const float* __restrict__ E1,
                                              const float* __restrict__ E2,
                                              const float* __restrict__ W,
                                              const float* __restrict__ x,
                                              unsigned short* __restrict__ adjp,
                                              float* __restrict__ rinv,
                                              unsigned short* __restrict__ yt) {
  __shared__ float rsum[8][16];
  __shared__ unsigned short wlds[128 * 136];  // W^T bf16 [o][f], f-pitch 136 (16B-aligned rows)
  const int bx = blockIdx.x;
  const int tid = threadIdx.x;
  const int lane = tid & 63, wv = tid >> 6;
  const int lr = lane & 15, lq = lane >> 4;

  if (bx >= 250) {
    // ---- stage W -> LDS as bf16 W^T (coalesced float4 reads, 8/thread) ----
    {
      const int fr = tid >> 5;   // 0..15
      const int o4 = tid & 31;   // 0..31
#pragma unroll
      for (int r8 = 0; r8 < 8; r8++) {
        const int f = fr + r8 * 16;
        float4 w4 = *(const float4*)&W[(size_t)f * DOUT + o4 * 4];
        wlds[(o4 * 4 + 0) * 136 + f] = f2bf(w4.x);
        wlds[(o4 * 4 + 1) * 136 + f] = f2bf(w4.y);
        wlds[(o4 * 4 + 2) * 136 + f] = f2bf(w4.z);
        wlds[(o4 * 4 + 3) * 136 + f] = f2bf(w4.w);
      }
    }
    __syncthreads();

    // ---- y^T GEMM: block -> (batch b, 256-m chunk) ----
    const int yi = bx - 250;        // 0..127
    const int b  = yi >> 4;         // 0..7
    const int m0 = (yi & 15) * 256; // 0..3840
    const int mh = wv >> 2;         // 0..1 : 32-m half within 64-m subchunk
    const int os = wv & 3;          // 0..3 : 32-o strip

    bf16x8 af[2][4];  // [ot][ks] : A-frags = W^T[o][f] from LDS
#pragma unroll
    for (int ot = 0; ot < 2; ot++) {
      const int ob = os * 32 + ot * 16 + lr;
#pragma unroll
      for (int ks = 0; ks < 4; ks++)
        af[ot][ks] = *(const bf16x8*)&wlds[ob * 136 + ks * 32 + lq * 8];
    }

#pragma unroll
    for (int cc = 0; cc < 4; cc++) {
#pragma unroll
      for (int mtile = 0; mtile < 2; mtile++) {
        const int mb = m0 + cc * 64 + mh * 32 + mtile * 16;
        const int m = mb + lr;
        bf16x8 bx8[4];
        if (m < NSEN) {
          const float* xp = &x[((size_t)b * NSEN + m) * DIN + lq * 8];
#pragma unroll
          for (int ks = 0; ks < 4; ks++) {
            float4 v0 = *(const float4*)(xp + ks * 32);
            float4 v1 = *(const float4*)(xp + ks * 32 + 4);
            bx8[ks][0] = (short)f2bf(v0.x); bx8[ks][1] = (short)f2bf(v0.y);
            bx8[ks][2] = (short)f2bf(v0.z); bx8[ks][3] = (short)f2bf(v0.w);
            bx8[ks][4] = (short)f2bf(v1.x); bx8[ks][5] = (short)f2bf(v1.y);
            bx8[ks][6] = (short)f2bf(v1.z); bx8[ks][7] = (short)f2bf(v1.w);
          }
        } else {
#pragma unroll
          for (int ks = 0; ks < 4; ks++)
#pragma unroll
            for (int j = 0; j < 8; j++) bx8[ks][j] = 0;
        }
#pragma unroll
        for (int ot = 0; ot < 2; ot++) {
          f32x4 c = (f32x4){0.f, 0.f, 0.f, 0.f};
#pragma unroll
          for (int ks = 0; ks < 4; ks++)
            c = __builtin_amdgcn_mfma_f32_16x16x32_bf16(af[ot][ks], bx8[ks], c, 0, 0, 0);
          // C: col = lr (m-local), row = lq*4+i (o-local)
#pragma unroll
          for (int i = 0; i < 4; i++)
            yt[(size_t)(b * 128 + os * 32 + ot * 16 + lq * 4 + i) * NP + mb + lr] = f2bf(c[i]);
        }
      }
    }
    return;
  }

  // ---- adjacency rows n0..n0+15 (MFMA hi/lo split) ----
  const int n0 = bx * 16;

  float a[8];
  {
    const float* e1p = &E1[(size_t)(n0 + lr) * EDIM + (lq & 1) * 8];
    *(float4*)&a[0] = *(const float4*)e1p;
    *(float4*)&a[4] = *(const float4*)(e1p + 4);
  }
  bf16x8 af1, af2;
#pragma unroll
  for (int j = 0; j < 8; j++) {
    unsigned short hs = f2bf(a[j]);
    af1[j] = (short)hs;
    float lo = a[j] - bf2f(hs);
    af2[j] = (lq < 2) ? (short)f2bf(lo) : (short)0;
  }

  float rs[4] = {0.f, 0.f, 0.f, 0.f};
  for (int t = wv; t < NSEN / 16; t += 8) {
    const int m = t * 16 + lr;
    float bv[8];
    const float* e2p = &E2[(size_t)m * EDIM + (lq & 1) * 8];
    *(float4*)&bv[0] = *(const float4*)e2p;
    *(float4*)&bv[4] = *(const float4*)(e2p + 4);
    bf16x8 bfrag;
#pragma unroll
    for (int j = 0; j < 8; j++) {
      unsigned short hs = f2bf(bv[j]);
      if (lq < 2) bfrag[j] = (short)hs;
      else        bfrag[j] = (short)f2bf(bv[j] - bf2f(hs));
    }
    f32x4 c = (f32x4){0.f, 0.f, 0.f, 0.f};
    c = __builtin_amdgcn_mfma_f32_16x16x32_bf16(af1, bfrag, c, 0, 0, 0);
    c = __builtin_amdgcn_mfma_f32_16x16x32_bf16(af2, bfrag, c, 0, 0, 0);
#pragma unroll
    for (int i = 0; i < 4; i++) {
      float p = __expf(fmaxf(c[i], 0.f));
      rs[i] += p;
      adjp[(size_t)(n0 + lq * 4 + i) * NP + t * 16 + lr] = f2bf(p);
    }
  }
  for (int i = tid; i < 16 * (NP - NSEN); i += 512) {
    int r = i / (NP - NSEN), c = i % (NP - NSEN);
    adjp[(size_t)(n0 + r) * NP + NSEN + c] = 0;
  }
#pragma unroll
  for (int i = 0; i < 4; i++) {
    rs[i] += __shfl_xor(rs[i], 1, 64);
    rs[i] += __shfl_xor(rs[i], 2, 64);
    rs[i] += __shfl_xor(rs[i], 4, 64);
    rs[i] += __shfl_xor(rs[i], 8, 64);
  }
  if (lr == 0) {
#pragma unroll
    for (int i = 0; i < 4; i++) rsum[wv][lq * 4 + i] = rs[i];
  }
  __syncthreads();
  if (tid < 16) {
    float s = 0.f;
#pragma unroll
    for (int w = 0; w < 8; w++) s += rsum[w][tid];
    rinv[n0 + tid] = 1.0f / s;
  }
}

// ---------------- Kernel 2: split-K partial GEMM  part[kh] = P[:,kh] @ yt^T ------
// (unchanged from R8/R9 — proven 785 TF / 43.8 us, FETCH 34 MB, 0 bank conflicts)
__global__ __launch_bounds__(256, 2) void k_gemm1(const unsigned short* __restrict__ A,
                                                  const unsigned short* __restrict__ Bt,
                                                  unsigned short* __restrict__ part) {
  __shared__ __align__(16) unsigned short smem[32768];  // 64 KB: A 2x8192 | B 2x8192
  const int tid = threadIdx.x;
  const int lane = tid & 63, wv = tid >> 6;
  const int wr = wv >> 1, wc = wv & 1;     // 2 x 2 wave grid, wave tile 64x64
  const int lr = lane & 15, lq = lane >> 4;
  const int gx = blockIdx.x;               // 0..63 = 2*mtile + kh
  const int m0 = (gx >> 1) * 128;
  const int kb0 = (gx & 1) * 2048;
  const int b  = blockIdx.y;
  const int c0 = b * 128;
  unsigned short* tA0 = smem;            // 2 * 8192 shorts
  unsigned short* tB0 = smem + 16384;    // 2 * 8192 shorts

  f32x4 acc[4][4];
#pragma unroll
  for (int p = 0; p < 4; p++)
#pragma unroll
    for (int q = 0; q < 4; q++) acc[p][q] = (f32x4){0.f, 0.f, 0.f, 0.f};

#define STAGE(bufi, kb)                                                              \
  {                                                                                  \
    _Pragma("unroll")                                                                \
    for (int s = 0; s < 4; s++) {                                                    \
      int idx = s * 256 + tid;                                                       \
      int row = idx >> 3;                                                            \
      int kc = ((idx & 7) ^ (row & 7)) << 3;                                         \
      gl_lds16(&A[(size_t)(m0 + row) * NP + (kb) + kc], &tA0[(bufi)*8192 + idx*8]);  \
      gl_lds16(&Bt[(size_t)(c0 + row) * NP + (kb) + kc], &tB0[(bufi)*8192 + idx*8]); \
    }                                                                                \
  }

  STAGE(0, kb0);

  for (int it = 0; it < 32; ++it) {
    const int cur = it & 1;
    if (it < 31) {
      STAGE(cur ^ 1, kb0 + (it + 1) * 64);
      asm volatile("s_waitcnt vmcnt(8)" ::: "memory");
    } else {
      asm volatile("s_waitcnt vmcnt(0)" ::: "memory");
    }
    __builtin_amdgcn_s_barrier();

    bf16x8 af0[4], bf0[4], af1[4], bf1[4];
    {
      const int koff0 = (lq * 8) ^ ((lr & 7) << 3);
#pragma unroll
      for (int p = 0; p < 4; p++)
        af0[p] = *(const bf16x8*)&tA0[cur * 8192 + (wr * 64 + p * 16 + lr) * 64 + koff0];
#pragma unroll
      for (int q = 0; q < 4; q++)
        bf0[q] = *(const bf16x8*)&tB0[cur * 8192 + (wc * 64 + q * 16 + lr) * 64 + koff0];
    }
    __builtin_amdgcn_sched_barrier(0);
    {
      const int koff1 = (32 + lq * 8) ^ ((lr & 7) << 3);
#pragma unroll
      for (int p = 0; p < 4; p++)
        af1[p] = *(const bf16x8*)&tA0[cur * 8192 + (wr * 64 + p * 16 + lr) * 64 + koff1];
#pragma unroll
      for (int q = 0; q < 4; q++)
        bf1[q] = *(const bf16x8*)&tB0[cur * 8192 + (wc * 64 + q * 16 + lr) * 64 + koff1];
    }
    asm volatile("s_waitcnt lgkmcnt(8)" ::: "memory");
    __builtin_amdgcn_sched_barrier(0);
    __builtin_amdgcn_s_setprio(1);
#pragma unroll
    for (int p = 0; p < 4; p++)
#pragma unroll
      for (int q = 0; q < 4; q++)
        acc[p][q] = __builtin_amdgcn_mfma_f32_16x16x32_bf16(af0[p], bf0[q], acc[p][q], 0, 0, 0);
    asm volatile("s_waitcnt lgkmcnt(0)" ::: "memory");
    __builtin_amdgcn_sched_barrier(0);
#pragma unroll
    for (int p = 0; p < 4; p++)
#pragma unroll
      for (int q = 0; q < 4; q++)
        acc[p][q] = __builtin_amdgcn_mfma_f32_16x16x32_bf16(af1[p], bf1[q], acc[p][q], 0, 0, 0);
    __builtin_amdgcn_s_setprio(0);
    __builtin_amdgcn_s_barrier();
  }
#undef STAGE

  const int kh = gx & 1;
  unsigned short* pdst = part + ((size_t)(kh * BATCH + b) * NP + m0) * DIN;
#pragma unroll
  for (int p = 0; p < 4; p++)
#pragma unroll
    for (int q = 0; q < 4; q++) {
      const int col = wc * 64 + q * 16 + lr;
#pragma unroll
      for (int i = 0; i < 4; i++) {
        const int row = wr * 64 + p * 16 + lq * 4 + i;
        pdst[row * DIN + col] = f2bf(acc[p][q][i]);
      }
    }
}

// ---------------- Kernel 3: out = relu((p0+p1)*rinv + bias)  (pure elementwise) --
__global__ __launch_bounds__(256) void k_fin(const unsigned short* __restrict__ part,
                                             const float* __restrict__ rinv,
                                             const float* __restrict__ bias,
                                             float* __restrict__ out) {
  const int tid = threadIdx.x;
  const int nl = tid >> 4;        // 0..15 row within block
  const int ch = tid & 15;        // 0..15 chunk of 8 outputs
  const int n  = blockIdx.x * 16 + nl;   // < 4000
  const int b  = blockIdx.y;
  const size_t base = ((size_t)b * NP + n) * DIN + ch * 8;
  const size_t khoff = (size_t)BATCH * NP * DIN;

  bf16x8 p0 = *(const bf16x8*)&part[base];
  bf16x8 p1 = *(const bf16x8*)&part[khoff + base];
  const float rv = rinv[n];
  float4 bb0 = *(const float4*)&bias[ch * 8];
  float4 bb1 = *(const float4*)&bias[ch * 8 + 4];
  float r[8];
#pragma unroll
  for (int j = 0; j < 8; j++) {
    float bbj = (j < 4) ? ((const float*)&bb0)[j] : ((const float*)&bb1)[j - 4];
    r[j] = fmaxf((bf2f((unsigned short)p0[j]) + bf2f((unsigned short)p1[j])) * rv + bbj, 0.f);
  }
  float* op = &out[((size_t)b * NSEN + n) * DOUT + ch * 8];
  *(float4*)op       = make_float4(r[0], r[1], r[2], r[3]);
  *(float4*)(op + 4) = make_float4(r[4], r[5], r[6], r[7]);
}

// ---------------- launch ---------------------------------------------------------
extern "C" void kernel_launch(void* const* d_in, const int* in_sizes, int n_in,
                              void* d_out, int out_size, void* d_ws, size_t ws_size,
                              hipStream_t stream) {
  const float* x    = (const float*)d_in[0];
  const float* E1   = (const float*)d_in[1];
  const float* E2   = (const float*)d_in[2];
  const float* W    = (const float*)d_in[3];
  const float* bias = (const float*)d_in[4];
  float* out = (float*)d_out;

  char* ws = (char*)d_ws;
  // layout: adjp 33554432 | yt 8388608 | rinv 16384 | part 16777216  (~57 MiB)
  unsigned short* adjp = (unsigned short*)(ws);
  unsigned short* yt   = (unsigned short*)(ws + 33554432);
  float*          rinv = (float*)(ws + 33554432 + 8388608);
  unsigned short* part = (unsigned short*)(ws + 33554432 + 8388608 + 16384);

  k_prep<<<dim3(378), dim3(512), 0, stream>>>(E1, E2, W, x, adjp, rinv, yt);
  k_gemm1<<<dim3(64, BATCH), dim3(256), 0, stream>>>(adjp, yt, part);
  k_fin<<<dim3(250, BATCH), dim3(256), 0, stream>>>(part, rinv, bias, out);
}